// Round 5
// baseline (139.706 us; speedup 1.0000x reference)
//
#include <hip/hip_runtime.h>
#include <hip/hip_bf16.h>
#include <math.h>

// Problem constants (fixed by the reference).
#define B_  16
#define N_  16384
#define D_  64
#define K_  64
#define OUT_PER_B (K_ + 2*K_*D_)   // 8256
#define CHUNKS 64                  // 1024 blocks = EXACTLY 4 blocks/CU x 256 CU
#define NTILES (N_ / CHUNKS / 64)  // 4

// ws layout: per (b,chunk) partial record at offset (b*CHUNKS+chunk)*PART_STRIDE:
//   f32 qsum[64] | bf16 qx[64*64] | bf16 qx2[64*64]   (16640 B)
#define PART_STRIDE (64*4 + 2*4096*2)   // 16640 bytes
#define PART_TOTAL  ((size_t)B_ * CHUNKS * PART_STRIDE)   // 17,039,360 B
// prep region appended after partials:
#define W_OFF   PART_TOTAL            // 16 KB packed wfrag [(kt*4+op)*64+lane]*16B
#define C0_OFF  (PART_TOTAL + 16384)  // 64 f32

typedef float f32x4 __attribute__((ext_vector_type(4)));
typedef short short8 __attribute__((ext_vector_type(8)));

union U8 { short8 s8; unsigned int u[4]; };

__device__ __forceinline__ unsigned short f2bf(float f) {
    union { float f; unsigned int u; } v; v.f = f;
    unsigned int r = v.u + 0x7FFFu + ((v.u >> 16) & 1u);   // round-to-nearest-even
    return (unsigned short)(r >> 16);
}

// packed RNE f32x2 -> bf16x2 (v_cvt_pk_bf16_f32 on gfx950)
__device__ __forceinline__ unsigned int f2bf2(float lo, float hi) {
    __hip_bfloat162 h = __float22bfloat162_rn(make_float2(lo, hi));
    unsigned int u;
    __builtin_memcpy(&u, &h, 4);
    return u;
}

__device__ __forceinline__ float bf2f(unsigned short u) {
    unsigned int v = ((unsigned int)u) << 16;
    float f;
    __builtin_memcpy(&f, &v, 4);
    return f;
}

// R11: prep hoisted out of fv_main. wfrag depends only on lane (identical for
// every wave of every block) -> compute ONCE here (16 KB) + c0s, store to ws.
__global__ __launch_bounds__(256) void fv_prep(const float* __restrict__ pi,
                                               const float* __restrict__ mu,
                                               const float* __restrict__ var,
                                               char* __restrict__ ws) {
    __shared__ float red[256];
    const int t = threadIdx.x;

    // c0 partial sums (exact replication of original summation order)
    {
        int k = t >> 2, pr = t & 3;
        float s = 0.0f;
        #pragma unroll
        for (int j = 0; j < 16; ++j) {
            int d = pr * 16 + j;
            float v = var[k * 64 + d];
            float m = mu[k * 64 + d];
            s += __logf(v) + m * m / v;
        }
        red[t] = s;
    }

    // wfrag for (lane = t&63, kt = t>>6): same per-element math as before.
    {
        const int lane = t & 63;
        const int kt   = t >> 6;
        const int r16  = lane & 15;
        const int q    = lane >> 4;
        const int k = 16 * kt + r16;
        const float* vr = var + k * 64 + 8 * q;
        const float* mr = mu  + k * 64 + 8 * q;
        float vv[16], mm[16];
        *(float4*)&vv[0]  = *(const float4*)(vr);
        *(float4*)&vv[4]  = *(const float4*)(vr + 4);
        *(float4*)&vv[8]  = *(const float4*)(vr + 32);
        *(float4*)&vv[12] = *(const float4*)(vr + 36);
        *(float4*)&mm[0]  = *(const float4*)(mr);
        *(float4*)&mm[4]  = *(const float4*)(mr + 4);
        *(float4*)&mm[8]  = *(const float4*)(mr + 32);
        *(float4*)&mm[12] = *(const float4*)(mr + 36);
        float iv[16];
        #pragma unroll
        for (int i = 0; i < 16; ++i) iv[i] = 1.0f / vv[i];
        U8 h0, h1, h2, h3;
        #pragma unroll
        for (int i = 0; i < 4; ++i) {
            h0.u[i] = f2bf2(-0.5f * iv[2*i],     -0.5f * iv[2*i + 1]);
            h1.u[i] = f2bf2(-0.5f * iv[8 + 2*i], -0.5f * iv[8 + 2*i + 1]);
            h2.u[i] = f2bf2(mm[2*i] * iv[2*i],   mm[2*i+1] * iv[2*i + 1]);
            h3.u[i] = f2bf2(mm[8+2*i] * iv[8+2*i], mm[8+2*i+1] * iv[8+2*i+1]);
        }
        short8* W = (short8*)(ws + W_OFF);
        W[(kt * 4 + 0) * 64 + lane] = h0.s8;
        W[(kt * 4 + 1) * 64 + lane] = h1.s8;
        W[(kt * 4 + 2) * 64 + lane] = h2.s8;
        W[(kt * 4 + 3) * 64 + lane] = h3.s8;
    }

    __syncthreads();
    if ((t & 3) == 0) {
        int k = t >> 2;
        float sum = red[4 * k] + red[4 * k + 1] + red[4 * k + 2] + red[4 * k + 3];
        // D*log(2*pi) = 117.6241322501981
        ((float*)(ws + C0_OFF))[k] = __logf(pi[k]) - 0.5f * (117.6241322502f + sum);
    }
}

// MFMA layouts (16x16x32 bf16, guide-verified):
//   A[m = lane&15][kk = (lane>>4)*8 + j]
//   B[kk = (lane>>4)*8 + j][n = lane&15]
//   C/D: col = lane&15, row = 4*(lane>>4) + reg
// R12: __launch_bounds__(256,4) -> combined VGPR+AGPR capped at 128
// = 4 waves/SIMD = 4 blocks/CU; 1024-block grid packs in ONE round (no tail).
// (256,3) was a pathology: 768 resident + 256-block straggler round at 1/CU.
// To fit 128 the explicit next-tile row-prefetch regs (16 VGPR) are dropped;
// at 16 waves/CU, TLP hides the row-load latency instead.
// Post-diet estimate: 32 AGPR acc + ~88 VGPR = ~120 combined. Guard metric:
// FETCH ~33 MB / WRITE ~17 MB (anything much bigger = spill -> revert).
__global__ __launch_bounds__(256, 4) void fv_main(const float* __restrict__ x,
                                                  char* __restrict__ partials) {
    __shared__ __align__(16) unsigned short QtS[2][64 * 72];  // double-buffered Q^T[k][p]
    __shared__ __align__(16) unsigned short wfS[4 * 4 * 64 * 8];  // 16 KB A-fragments
    __shared__ float qsum_s[4][64];

    const int t    = threadIdx.x;
    const int w    = t >> 6;        // wave 0..3
    const int lane = t & 63;
    const int r16  = lane & 15;
    const int q    = lane >> 4;     // quad 0..3

    // ---- cooperative load of precomputed wfrag into LDS (16 KB, coalesced) ----
    {
        const float4* gw = (const float4*)(partials + W_OFF);
        float4* sw = (float4*)wfS;
        #pragma unroll
        for (int i = 0; i < 4; ++i) sw[i * 256 + t] = gw[i * 256 + t];
    }
    // c0 row constants straight from global (256 B, L2-broadcast)
    f32x4 c0v[4];
    {
        const float* c0g = (const float*)(partials + C0_OFF);
        #pragma unroll
        for (int kt = 0; kt < 4; ++kt)
            c0v[kt] = *(const f32x4*)&c0g[16 * kt + 4 * q];
    }

    const int bi    = blockIdx.y;
    const int chunk = blockIdx.x;
    const int ppb   = N_ / CHUNKS;
    const float* xb = x + ((size_t)bi * N_ + (size_t)chunk * ppb) * D_;

    f32x4 accX[4]  = {};       // Qx  : k rows, d col = 16w + r16
    f32x4 accX2[4] = {};       // Qx2
    float qsacc[4][4] = {};    // per-lane Q sums (ks: 16kt + 4q + rr)

    const int rowoff = (16 * w + r16) * D_ + 8 * q;   // phase-1 row base
    const int dcol   = 16 * w + r16;                  // phase-2 column

    const short8* wfp = (const short8*)wfS;   // [(kt*4+op)*64 + lane]

    __syncthreads();            // wfS ready

    #pragma unroll 2
    for (int tile = 0; tile < NTILES; ++tile) {
        const float* xt = xb + (size_t)tile * 64 * D_;

        // ---- row loads for CURRENT tile (needed first, issue first) ----
        float4 va, vb, vc, vd;
        {
            const float* xr = xt + rowoff;
            va = *(const float4*)(xr);
            vb = *(const float4*)(xr + 4);
            vc = *(const float4*)(xr + 32);
            vd = *(const float4*)(xr + 36);
        }

        // ---- phase-2 column loads, issued early (consumed after the barrier) ----
        float vle[16];
        {
            const float* xc = xt + dcol;
            #pragma unroll
            for (int c = 0; c < 2; ++c)
                #pragma unroll
                for (int j = 0; j < 8; ++j)
                    vle[8 * c + j] = xc[(32 * c + 8 * q + j) * D_];
        }

        // ================= phase 1: S^T[k][p] =================
        U8 fxa, fxb, fx2a, fx2b;
        fxa.u[0]  = f2bf2(va.x, va.y);           fxa.u[1]  = f2bf2(va.z, va.w);
        fxa.u[2]  = f2bf2(vb.x, vb.y);           fxa.u[3]  = f2bf2(vb.z, vb.w);
        fxb.u[0]  = f2bf2(vc.x, vc.y);           fxb.u[1]  = f2bf2(vc.z, vc.w);
        fxb.u[2]  = f2bf2(vd.x, vd.y);           fxb.u[3]  = f2bf2(vd.z, vd.w);
        fx2a.u[0] = f2bf2(va.x*va.x, va.y*va.y); fx2a.u[1] = f2bf2(va.z*va.z, va.w*va.w);
        fx2a.u[2] = f2bf2(vb.x*vb.x, vb.y*vb.y); fx2a.u[3] = f2bf2(vb.z*vb.z, vb.w*vb.w);
        fx2b.u[0] = f2bf2(vc.x*vc.x, vc.y*vc.y); fx2b.u[1] = f2bf2(vc.z*vc.z, vc.w*vc.w);
        fx2b.u[2] = f2bf2(vd.x*vd.x, vd.y*vd.y); fx2b.u[3] = f2bf2(vd.z*vd.z, vd.w*vd.w);

        float sc[4][4];
        #pragma unroll
        for (int kt = 0; kt < 4; ++kt) {
            f32x4 a = c0v[kt];
            a = __builtin_amdgcn_mfma_f32_16x16x32_bf16(wfp[(kt*4+0)*64 + lane], fx2a.s8, a, 0, 0, 0);
            a = __builtin_amdgcn_mfma_f32_16x16x32_bf16(wfp[(kt*4+1)*64 + lane], fx2b.s8, a, 0, 0, 0);
            a = __builtin_amdgcn_mfma_f32_16x16x32_bf16(wfp[(kt*4+2)*64 + lane], fxa.s8,  a, 0, 0, 0);
            a = __builtin_amdgcn_mfma_f32_16x16x32_bf16(wfp[(kt*4+3)*64 + lane], fxb.s8,  a, 0, 0, 0);
            sc[kt][0] = a[0]; sc[kt][1] = a[1]; sc[kt][2] = a[2]; sc[kt][3] = a[3];
        }

        // ---- softmax over k: 16 in-lane values + lanes^16,^32 (same point p) ----
        float mx = sc[0][0];
        #pragma unroll
        for (int kt = 0; kt < 4; ++kt)
            #pragma unroll
            for (int rr = 0; rr < 4; ++rr) mx = fmaxf(mx, sc[kt][rr]);
        mx = fmaxf(mx, __shfl_xor(mx, 16));
        mx = fmaxf(mx, __shfl_xor(mx, 32));
        float z = 0.0f;
        #pragma unroll
        for (int kt = 0; kt < 4; ++kt)
            #pragma unroll
            for (int rr = 0; rr < 4; ++rr) {
                sc[kt][rr] = __expf(sc[kt][rr] - mx);
                z += sc[kt][rr];
            }
        z += __shfl_xor(z, 16);
        z += __shfl_xor(z, 32);
        float inv = 1.0f / z;
        const int p = 16 * w + r16;
        unsigned short* Qb = QtS[tile & 1];
        #pragma unroll
        for (int kt = 0; kt < 4; ++kt) {
            #pragma unroll
            for (int rr = 0; rr < 4; rr += 2) {
                float q0 = sc[kt][rr] * inv;
                float q1 = sc[kt][rr + 1] * inv;
                qsacc[kt][rr]     += q0;
                qsacc[kt][rr + 1] += q1;
                unsigned int pk = f2bf2(q0, q1);
                Qb[(16 * kt + 4 * q + rr)     * 72 + p] = (unsigned short)pk;
                Qb[(16 * kt + 4 * q + rr + 1) * 72 + p] = (unsigned short)(pk >> 16);
            }
        }

        // barrier WITHOUT vmcnt(0) drain (LDS visibility only) — keeps loads in flight
        asm volatile("s_waitcnt lgkmcnt(0)\n\ts_barrier" ::: "memory");

        // ================= phase 2: Qx[k][d], Qx2[k][d] =================
        U8 fxp0, fxp1, fx2p0, fx2p1;
        #pragma unroll
        for (int i = 0; i < 4; ++i) {
            float a0 = vle[2 * i], a1 = vle[2 * i + 1];
            float b0 = vle[8 + 2 * i], b1 = vle[8 + 2 * i + 1];
            fxp0.u[i]  = f2bf2(a0, a1);
            fxp1.u[i]  = f2bf2(b0, b1);
            fx2p0.u[i] = f2bf2(a0 * a0, a1 * a1);
            fx2p1.u[i] = f2bf2(b0 * b0, b1 * b1);
        }
        #pragma unroll
        for (int kt = 0; kt < 4; ++kt) {
            const unsigned short* qr = &Qb[(16 * kt + r16) * 72 + 8 * q];
            short8 aq0 = *(const short8*)(const void*)(qr);
            short8 aq1 = *(const short8*)(const void*)(qr + 32);
            accX[kt]  = __builtin_amdgcn_mfma_f32_16x16x32_bf16(aq0, fxp0.s8,  accX[kt],  0, 0, 0);
            accX2[kt] = __builtin_amdgcn_mfma_f32_16x16x32_bf16(aq0, fx2p0.s8, accX2[kt], 0, 0, 0);
            accX[kt]  = __builtin_amdgcn_mfma_f32_16x16x32_bf16(aq1, fxp1.s8,  accX[kt],  0, 0, 0);
            accX2[kt] = __builtin_amdgcn_mfma_f32_16x16x32_bf16(aq1, fx2p1.s8, accX2[kt], 0, 0, 0);
        }
    }

    // ---- write partials: f32 qsum[64] | bf16 qx[4096] | bf16 qx2[4096] ----
    char* rec = partials + ((size_t)bi * CHUNKS + chunk) * PART_STRIDE;
    float* part_qs = (float*)rec;
    unsigned short* part_qx  = (unsigned short*)(rec + 256);
    unsigned short* part_qx2 = part_qx + 4096;
    #pragma unroll
    for (int kt = 0; kt < 4; ++kt)
        #pragma unroll
        for (int rr = 0; rr < 4; ++rr) {
            int k = 16 * kt + 4 * q + rr;
            part_qx [k * 64 + 16 * w + r16] = f2bf(accX[kt][rr]);
            part_qx2[k * 64 + 16 * w + r16] = f2bf(accX2[kt][rr]);
        }
    #pragma unroll
    for (int kt = 0; kt < 4; ++kt)
        #pragma unroll
        for (int rr = 0; rr < 4; ++rr) {
            float v = qsacc[kt][rr];
            v += __shfl_xor(v, 1);
            v += __shfl_xor(v, 2);
            v += __shfl_xor(v, 4);
            v += __shfl_xor(v, 8);
            if (r16 == 0) qsum_s[w][16 * kt + 4 * q + rr] = v;
        }
    __syncthreads();
    if (t < 64)
        part_qs[t] = qsum_s[0][t] + qsum_s[1][t] + qsum_s[2][t] + qsum_s[3][t];
}

// Finalize: one block per (b,k). 1024 blocks x 4 waves. Each thread owns one d
// and 16 chunks (strided, coalesced 128B/wave reads), LDS-reduce over the 4
// chunk-groups, coalesced writes of d_mu/d_sigma rows.
__global__ __launch_bounds__(256) void fv_finalize(const float* __restrict__ pi,
                                                   const float* __restrict__ mu,
                                                   const float* __restrict__ var,
                                                   const char* __restrict__ partials,
                                                   float* __restrict__ out) {
    const int bk = blockIdx.x;
    const int b  = bk >> 6;
    const int k  = bk & 63;
    const int t  = threadIdx.x;
    const int d  = t & 63;
    const int cg = t >> 6;              // chunk-group 0..3

    const char* base = partials + (size_t)b * CHUNKS * PART_STRIDE;

    float qs = 0.0f, qx = 0.0f, qx2 = 0.0f;
    for (int c = cg; c < CHUNKS; c += 4) {
        const char* r = base + (size_t)c * PART_STRIDE;
        qs  += ((const float*)r)[k];
        qx  += bf2f(((const unsigned short*)(r + 256))[k * 64 + d]);
        qx2 += bf2f(((const unsigned short*)(r + 256))[4096 + k * 64 + d]);
    }

    __shared__ float sQx[4][64];
    __shared__ float sQx2[4][64];
    __shared__ float sQs[4];
    sQx[cg][d]  = qx;
    sQx2[cg][d] = qx2;
    if (d == 0) sQs[cg] = qs;
    __syncthreads();

    if (cg == 0) {
        const float invN = 1.0f / (float)N_;
        float QX  = sQx[0][d]  + sQx[1][d]  + sQx[2][d]  + sQx[3][d];
        float QX2 = sQx2[0][d] + sQx2[1][d] + sQx2[2][d] + sQx2[3][d];
        float QS  = sQs[0] + sQs[1] + sQs[2] + sQs[3];
        float m = mu[k * 64 + d];
        float v = var[k * 64 + d];
        float* ob = out + (size_t)b * OUT_PER_B;
        if (d == 0) ob[k] = QS * invN - pi[k];
        ob[64 + k * 64 + d]        = (QX - QS * m) * invN;
        ob[64 + 4096 + k * 64 + d] = (-QX2 - QS * m * m + QS * v + 2.0f * QX * m) * invN;
    }
}

extern "C" void kernel_launch(void* const* d_in, const int* in_sizes, int n_in,
                              void* d_out, int out_size, void* d_ws, size_t ws_size,
                              hipStream_t stream) {
    const float* x   = (const float*)d_in[0];
    const float* pi  = (const float*)d_in[1];
    const float* mu  = (const float*)d_in[2];
    const float* var = (const float*)d_in[3];
    char* ws = (char*)d_ws;

    fv_prep<<<1, 256, 0, stream>>>(pi, mu, var, ws);
    fv_main<<<dim3(CHUNKS, B_), 256, 0, stream>>>(x, ws);
    fv_finalize<<<B_ * K_, 256, 0, stream>>>(pi, mu, var, ws, (float*)d_out);
}

// Round 6
// 120.079 us; speedup vs baseline: 1.1635x; 1.1635x over previous
//
#include <hip/hip_runtime.h>
#include <hip/hip_bf16.h>
#include <math.h>

// Problem constants (fixed by the reference).
#define B_  16
#define N_  16384
#define D_  64
#define K_  64
#define OUT_PER_B (K_ + 2*K_*D_)   // 8256
#define CHUNKS 64                  // 1024 blocks = EXACTLY 4 blocks/CU x 256 CU
#define NTILES (N_ / CHUNKS / 64)  // 4

// ws layout: per (b,chunk) partial record at offset (b*CHUNKS+chunk)*PART_STRIDE:
//   f32 qsum[64] | bf16 qx[64*64] | bf16 qx2[64*64]   (16640 B)
#define PART_STRIDE (64*4 + 2*4096*2)   // 16640 bytes
#define PART_TOTAL  ((size_t)B_ * CHUNKS * PART_STRIDE)   // 17,039,360 B
// prep region appended after partials:
#define W_OFF   PART_TOTAL            // 16 KB packed wfrag [(kt*4+op)*64+lane]*16B
#define C0_OFF  (PART_TOTAL + 16384)  // 64 f32

typedef float f32x4 __attribute__((ext_vector_type(4)));
typedef short short8 __attribute__((ext_vector_type(8)));

union U8 { short8 s8; unsigned int u[4]; };

__device__ __forceinline__ unsigned short f2bf(float f) {
    union { float f; unsigned int u; } v; v.f = f;
    unsigned int r = v.u + 0x7FFFu + ((v.u >> 16) & 1u);   // round-to-nearest-even
    return (unsigned short)(r >> 16);
}

// packed RNE f32x2 -> bf16x2 (v_cvt_pk_bf16_f32 on gfx950)
__device__ __forceinline__ unsigned int f2bf2(float lo, float hi) {
    __hip_bfloat162 h = __float22bfloat162_rn(make_float2(lo, hi));
    unsigned int u;
    __builtin_memcpy(&u, &h, 4);
    return u;
}

__device__ __forceinline__ float bf2f(unsigned short u) {
    unsigned int v = ((unsigned int)u) << 16;
    float f;
    __builtin_memcpy(&f, &v, 4);
    return f;
}

// Prep hoisted out of fv_main (R11). wfrag depends only on lane (identical for
// every wave of every block) -> compute ONCE here (16 KB) + c0s, store to ws.
__global__ __launch_bounds__(256) void fv_prep(const float* __restrict__ pi,
                                               const float* __restrict__ mu,
                                               const float* __restrict__ var,
                                               char* __restrict__ ws) {
    __shared__ float red[256];
    const int t = threadIdx.x;

    // c0 partial sums (exact replication of original summation order)
    {
        int k = t >> 2, pr = t & 3;
        float s = 0.0f;
        #pragma unroll
        for (int j = 0; j < 16; ++j) {
            int d = pr * 16 + j;
            float v = var[k * 64 + d];
            float m = mu[k * 64 + d];
            s += __logf(v) + m * m / v;
        }
        red[t] = s;
    }

    // wfrag for (lane = t&63, kt = t>>6): same per-element math as before.
    {
        const int lane = t & 63;
        const int kt   = t >> 6;
        const int r16  = lane & 15;
        const int q    = lane >> 4;
        const int k = 16 * kt + r16;
        const float* vr = var + k * 64 + 8 * q;
        const float* mr = mu  + k * 64 + 8 * q;
        float vv[16], mm[16];
        *(float4*)&vv[0]  = *(const float4*)(vr);
        *(float4*)&vv[4]  = *(const float4*)(vr + 4);
        *(float4*)&vv[8]  = *(const float4*)(vr + 32);
        *(float4*)&vv[12] = *(const float4*)(vr + 36);
        *(float4*)&mm[0]  = *(const float4*)(mr);
        *(float4*)&mm[4]  = *(const float4*)(mr + 4);
        *(float4*)&mm[8]  = *(const float4*)(mr + 32);
        *(float4*)&mm[12] = *(const float4*)(mr + 36);
        float iv[16];
        #pragma unroll
        for (int i = 0; i < 16; ++i) iv[i] = 1.0f / vv[i];
        U8 h0, h1, h2, h3;
        #pragma unroll
        for (int i = 0; i < 4; ++i) {
            h0.u[i] = f2bf2(-0.5f * iv[2*i],     -0.5f * iv[2*i + 1]);
            h1.u[i] = f2bf2(-0.5f * iv[8 + 2*i], -0.5f * iv[8 + 2*i + 1]);
            h2.u[i] = f2bf2(mm[2*i] * iv[2*i],   mm[2*i+1] * iv[2*i + 1]);
            h3.u[i] = f2bf2(mm[8+2*i] * iv[8+2*i], mm[8+2*i+1] * iv[8+2*i+1]);
        }
        short8* W = (short8*)(ws + W_OFF);
        W[(kt * 4 + 0) * 64 + lane] = h0.s8;
        W[(kt * 4 + 1) * 64 + lane] = h1.s8;
        W[(kt * 4 + 2) * 64 + lane] = h2.s8;
        W[(kt * 4 + 3) * 64 + lane] = h3.s8;
    }

    __syncthreads();
    if ((t & 3) == 0) {
        int k = t >> 2;
        float sum = red[4 * k] + red[4 * k + 1] + red[4 * k + 2] + red[4 * k + 3];
        // D*log(2*pi) = 117.6241322501981
        ((float*)(ws + C0_OFF))[k] = __logf(pi[k]) - 0.5f * (117.6241322502f + sum);
    }
}

// MFMA layouts (16x16x32 bf16, guide-verified):
//   A[m = lane&15][kk = (lane>>4)*8 + j]
//   B[kk = (lane>>4)*8 + j][n = lane&15]
//   C/D: col = lane&15, row = 4*(lane>>4) + reg
// R13: (256,4) retained (1024 blocks = one packed round), but with the
// register diet R12 missed:
//  - vle column loads issued AFTER softmax, just before the barrier (still
//    vmcnt-in-flight across the lgkmcnt-only barrier) -> 16 fewer long-live regs
//  - tile loop forced unroll 1 (unroll 2 doubled transient ranges; the
//    prefetch regs that needed it are gone). QtS[tile&1] is LDS addressing,
//    not reg-array indexing -> no scratch risk.
// Peak estimate: fx(32 transient)+sc(16)+qsacc(16)+acc(32 AGPR)+c0v(16)
// +addr/misc(~12) ~= 112 combined < 128.
// Guard: FETCH ~34 MB / WRITE ~17 MB. Inflation = spill -> revert to (256,3).
__global__ __launch_bounds__(256, 4) void fv_main(const float* __restrict__ x,
                                                  char* __restrict__ partials) {
    __shared__ __align__(16) unsigned short QtS[2][64 * 72];  // double-buffered Q^T[k][p]
    __shared__ __align__(16) unsigned short wfS[4 * 4 * 64 * 8];  // 16 KB A-fragments
    __shared__ float qsum_s[4][64];

    const int t    = threadIdx.x;
    const int w    = t >> 6;        // wave 0..3
    const int lane = t & 63;
    const int r16  = lane & 15;
    const int q    = lane >> 4;     // quad 0..3

    // ---- cooperative load of precomputed wfrag into LDS (16 KB, coalesced) ----
    {
        const float4* gw = (const float4*)(partials + W_OFF);
        float4* sw = (float4*)wfS;
        #pragma unroll
        for (int i = 0; i < 4; ++i) sw[i * 256 + t] = gw[i * 256 + t];
    }
    // c0 row constants straight from global (256 B, L2-broadcast)
    f32x4 c0v[4];
    {
        const float* c0g = (const float*)(partials + C0_OFF);
        #pragma unroll
        for (int kt = 0; kt < 4; ++kt)
            c0v[kt] = *(const f32x4*)&c0g[16 * kt + 4 * q];
    }

    const int bi    = blockIdx.y;
    const int chunk = blockIdx.x;
    const int ppb   = N_ / CHUNKS;
    const float* xb = x + ((size_t)bi * N_ + (size_t)chunk * ppb) * D_;

    f32x4 accX[4]  = {};       // Qx  : k rows, d col = 16w + r16
    f32x4 accX2[4] = {};       // Qx2
    float qsacc[4][4] = {};    // per-lane Q sums (ks: 16kt + 4q + rr)

    const int rowoff = (16 * w + r16) * D_ + 8 * q;   // phase-1 row base
    const int dcol   = 16 * w + r16;                  // phase-2 column

    const short8* wfp = (const short8*)wfS;   // [(kt*4+op)*64 + lane]

    __syncthreads();            // wfS ready

    #pragma unroll 1
    for (int tile = 0; tile < NTILES; ++tile) {
        const float* xt = xb + (size_t)tile * 64 * D_;

        // ---- row loads for CURRENT tile ----
        float4 va, vb, vc, vd;
        {
            const float* xr = xt + rowoff;
            va = *(const float4*)(xr);
            vb = *(const float4*)(xr + 4);
            vc = *(const float4*)(xr + 32);
            vd = *(const float4*)(xr + 36);
        }

        // ================= phase 1: S^T[k][p] =================
        U8 fxa, fxb, fx2a, fx2b;
        fxa.u[0]  = f2bf2(va.x, va.y);           fxa.u[1]  = f2bf2(va.z, va.w);
        fxa.u[2]  = f2bf2(vb.x, vb.y);           fxa.u[3]  = f2bf2(vb.z, vb.w);
        fxb.u[0]  = f2bf2(vc.x, vc.y);           fxb.u[1]  = f2bf2(vc.z, vc.w);
        fxb.u[2]  = f2bf2(vd.x, vd.y);           fxb.u[3]  = f2bf2(vd.z, vd.w);
        fx2a.u[0] = f2bf2(va.x*va.x, va.y*va.y); fx2a.u[1] = f2bf2(va.z*va.z, va.w*va.w);
        fx2a.u[2] = f2bf2(vb.x*vb.x, vb.y*vb.y); fx2a.u[3] = f2bf2(vb.z*vb.z, vb.w*vb.w);
        fx2b.u[0] = f2bf2(vc.x*vc.x, vc.y*vc.y); fx2b.u[1] = f2bf2(vc.z*vc.z, vc.w*vc.w);
        fx2b.u[2] = f2bf2(vd.x*vd.x, vd.y*vd.y); fx2b.u[3] = f2bf2(vd.z*vd.z, vd.w*vd.w);

        float sc[4][4];
        #pragma unroll
        for (int kt = 0; kt < 4; ++kt) {
            f32x4 a = c0v[kt];
            a = __builtin_amdgcn_mfma_f32_16x16x32_bf16(wfp[(kt*4+0)*64 + lane], fx2a.s8, a, 0, 0, 0);
            a = __builtin_amdgcn_mfma_f32_16x16x32_bf16(wfp[(kt*4+1)*64 + lane], fx2b.s8, a, 0, 0, 0);
            a = __builtin_amdgcn_mfma_f32_16x16x32_bf16(wfp[(kt*4+2)*64 + lane], fxa.s8,  a, 0, 0, 0);
            a = __builtin_amdgcn_mfma_f32_16x16x32_bf16(wfp[(kt*4+3)*64 + lane], fxb.s8,  a, 0, 0, 0);
            sc[kt][0] = a[0]; sc[kt][1] = a[1]; sc[kt][2] = a[2]; sc[kt][3] = a[3];
        }

        // ---- softmax over k: 16 in-lane values + lanes^16,^32 (same point p) ----
        float mx = sc[0][0];
        #pragma unroll
        for (int kt = 0; kt < 4; ++kt)
            #pragma unroll
            for (int rr = 0; rr < 4; ++rr) mx = fmaxf(mx, sc[kt][rr]);
        mx = fmaxf(mx, __shfl_xor(mx, 16));
        mx = fmaxf(mx, __shfl_xor(mx, 32));
        float z = 0.0f;
        #pragma unroll
        for (int kt = 0; kt < 4; ++kt)
            #pragma unroll
            for (int rr = 0; rr < 4; ++rr) {
                sc[kt][rr] = __expf(sc[kt][rr] - mx);
                z += sc[kt][rr];
            }
        z += __shfl_xor(z, 16);
        z += __shfl_xor(z, 32);
        float inv = 1.0f / z;

        // ---- phase-2 column loads: issued HERE (post-softmax, short live
        //      range); stay vmcnt-in-flight across the lgkmcnt-only barrier ----
        float vle[16];
        {
            const float* xc = xt + dcol;
            #pragma unroll
            for (int c = 0; c < 2; ++c)
                #pragma unroll
                for (int j = 0; j < 8; ++j)
                    vle[8 * c + j] = xc[(32 * c + 8 * q + j) * D_];
        }

        const int p = 16 * w + r16;
        unsigned short* Qb = QtS[tile & 1];
        #pragma unroll
        for (int kt = 0; kt < 4; ++kt) {
            #pragma unroll
            for (int rr = 0; rr < 4; rr += 2) {
                float q0 = sc[kt][rr] * inv;
                float q1 = sc[kt][rr + 1] * inv;
                qsacc[kt][rr]     += q0;
                qsacc[kt][rr + 1] += q1;
                unsigned int pk = f2bf2(q0, q1);
                Qb[(16 * kt + 4 * q + rr)     * 72 + p] = (unsigned short)pk;
                Qb[(16 * kt + 4 * q + rr + 1) * 72 + p] = (unsigned short)(pk >> 16);
            }
        }

        // barrier WITHOUT vmcnt(0) drain (LDS visibility only) — keeps loads in flight
        asm volatile("s_waitcnt lgkmcnt(0)\n\ts_barrier" ::: "memory");

        // ================= phase 2: Qx[k][d], Qx2[k][d] =================
        U8 fxp0, fxp1, fx2p0, fx2p1;
        #pragma unroll
        for (int i = 0; i < 4; ++i) {
            float a0 = vle[2 * i], a1 = vle[2 * i + 1];
            float b0 = vle[8 + 2 * i], b1 = vle[8 + 2 * i + 1];
            fxp0.u[i]  = f2bf2(a0, a1);
            fxp1.u[i]  = f2bf2(b0, b1);
            fx2p0.u[i] = f2bf2(a0 * a0, a1 * a1);
            fx2p1.u[i] = f2bf2(b0 * b0, b1 * b1);
        }
        #pragma unroll
        for (int kt = 0; kt < 4; ++kt) {
            const unsigned short* qr = &Qb[(16 * kt + r16) * 72 + 8 * q];
            short8 aq0 = *(const short8*)(const void*)(qr);
            short8 aq1 = *(const short8*)(const void*)(qr + 32);
            accX[kt]  = __builtin_amdgcn_mfma_f32_16x16x32_bf16(aq0, fxp0.s8,  accX[kt],  0, 0, 0);
            accX2[kt] = __builtin_amdgcn_mfma_f32_16x16x32_bf16(aq0, fx2p0.s8, accX2[kt], 0, 0, 0);
            accX[kt]  = __builtin_amdgcn_mfma_f32_16x16x32_bf16(aq1, fxp1.s8,  accX[kt],  0, 0, 0);
            accX2[kt] = __builtin_amdgcn_mfma_f32_16x16x32_bf16(aq1, fx2p1.s8, accX2[kt], 0, 0, 0);
        }
    }

    // ---- write partials: f32 qsum[64] | bf16 qx[4096] | bf16 qx2[4096] ----
    char* rec = partials + ((size_t)bi * CHUNKS + chunk) * PART_STRIDE;
    float* part_qs = (float*)rec;
    unsigned short* part_qx  = (unsigned short*)(rec + 256);
    unsigned short* part_qx2 = part_qx + 4096;
    #pragma unroll
    for (int kt = 0; kt < 4; ++kt)
        #pragma unroll
        for (int rr = 0; rr < 4; ++rr) {
            int k = 16 * kt + 4 * q + rr;
            part_qx [k * 64 + 16 * w + r16] = f2bf(accX[kt][rr]);
            part_qx2[k * 64 + 16 * w + r16] = f2bf(accX2[kt][rr]);
        }
    #pragma unroll
    for (int kt = 0; kt < 4; ++kt)
        #pragma unroll
        for (int rr = 0; rr < 4; ++rr) {
            float v = qsacc[kt][rr];
            v += __shfl_xor(v, 1);
            v += __shfl_xor(v, 2);
            v += __shfl_xor(v, 4);
            v += __shfl_xor(v, 8);
            if (r16 == 0) qsum_s[w][16 * kt + 4 * q + rr] = v;
        }
    __syncthreads();
    if (t < 64)
        part_qs[t] = qsum_s[0][t] + qsum_s[1][t] + qsum_s[2][t] + qsum_s[3][t];
}

// Finalize: one block per (b,k). 1024 blocks x 4 waves. Each thread owns one d
// and 16 chunks (strided, coalesced 128B/wave reads), LDS-reduce over the 4
// chunk-groups, coalesced writes of d_mu/d_sigma rows.
__global__ __launch_bounds__(256) void fv_finalize(const float* __restrict__ pi,
                                                   const float* __restrict__ mu,
                                                   const float* __restrict__ var,
                                                   const char* __restrict__ partials,
                                                   float* __restrict__ out) {
    const int bk = blockIdx.x;
    const int b  = bk >> 6;
    const int k  = bk & 63;
    const int t  = threadIdx.x;
    const int d  = t & 63;
    const int cg = t >> 6;              // chunk-group 0..3

    const char* base = partials + (size_t)b * CHUNKS * PART_STRIDE;

    float qs = 0.0f, qx = 0.0f, qx2 = 0.0f;
    for (int c = cg; c < CHUNKS; c += 4) {
        const char* r = base + (size_t)c * PART_STRIDE;
        qs  += ((const float*)r)[k];
        qx  += bf2f(((const unsigned short*)(r + 256))[k * 64 + d]);
        qx2 += bf2f(((const unsigned short*)(r + 256))[4096 + k * 64 + d]);
    }

    __shared__ float sQx[4][64];
    __shared__ float sQx2[4][64];
    __shared__ float sQs[4];
    sQx[cg][d]  = qx;
    sQx2[cg][d] = qx2;
    if (d == 0) sQs[cg] = qs;
    __syncthreads();

    if (cg == 0) {
        const float invN = 1.0f / (float)N_;
        float QX  = sQx[0][d]  + sQx[1][d]  + sQx[2][d]  + sQx[3][d];
        float QX2 = sQx2[0][d] + sQx2[1][d] + sQx2[2][d] + sQx2[3][d];
        float QS  = sQs[0] + sQs[1] + sQs[2] + sQs[3];
        float m = mu[k * 64 + d];
        float v = var[k * 64 + d];
        float* ob = out + (size_t)b * OUT_PER_B;
        if (d == 0) ob[k] = QS * invN - pi[k];
        ob[64 + k * 64 + d]        = (QX - QS * m) * invN;
        ob[64 + 4096 + k * 64 + d] = (-QX2 - QS * m * m + QS * v + 2.0f * QX * m) * invN;
    }
}

extern "C" void kernel_launch(void* const* d_in, const int* in_sizes, int n_in,
                              void* d_out, int out_size, void* d_ws, size_t ws_size,
                              hipStream_t stream) {
    const float* x   = (const float*)d_in[0];
    const float* pi  = (const float*)d_in[1];
    const float* mu  = (const float*)d_in[2];
    const float* var = (const float*)d_in[3];
    char* ws = (char*)d_ws;

    fv_prep<<<1, 256, 0, stream>>>(pi, mu, var, ws);
    fv_main<<<dim3(CHUNKS, B_), 256, 0, stream>>>(x, ws);
    fv_finalize<<<B_ * K_, 256, 0, stream>>>(pi, mu, var, ws, (float*)d_out);
}